// Round 1
// baseline (893.904 us; speedup 1.0000x reference)
//
#include <hip/hip_runtime.h>
#include <hip/hip_bf16.h>

// Problem constants
#define S_LEN 2048
#define HID 4096
#define NH 32
#define NKV 8
#define HD 128
#define KV_COLS (NKV * HD)   // 1024

typedef __bf16 bf16x8 __attribute__((ext_vector_type(8)));
typedef __bf16 bf16x4 __attribute__((ext_vector_type(4)));
typedef float f32x4 __attribute__((ext_vector_type(4)));

// ---------------------------------------------------------------------------
// cast fp32 -> bf16 (vectorized 4/thread)
// ---------------------------------------------------------------------------
__global__ void cast_bf16_kernel(const float* __restrict__ x, __bf16* __restrict__ y, int n) {
    int i = (blockIdx.x * blockDim.x + threadIdx.x) * 4;
    if (i < n) {
        float4 v = *reinterpret_cast<const float4*>(x + i);
        bf16x4 o;
        o.x = (__bf16)v.x; o.y = (__bf16)v.y; o.z = (__bf16)v.z; o.w = (__bf16)v.w;
        *reinterpret_cast<bf16x4*>(y + i) = o;
    }
}

// ---------------------------------------------------------------------------
// transpose + cast: W [K][N] fp32 -> WT [N][K] bf16
// ---------------------------------------------------------------------------
__global__ void transpose_cast_kernel(const float* __restrict__ W, __bf16* __restrict__ WT,
                                      int K, int N) {
    __shared__ float tile[32][33];
    int bx = blockIdx.x;  // over N/32
    int by = blockIdx.y;  // over K/32
    int tx = threadIdx.x; // 32
    int ty = threadIdx.y; // 8
    int n = bx * 32 + tx;
#pragma unroll
    for (int i = 0; i < 4; i++) {
        int k = by * 32 + ty + i * 8;
        tile[ty + i * 8][tx] = W[(size_t)k * N + n];
    }
    __syncthreads();
    int k2 = by * 32 + tx;
#pragma unroll
    for (int i = 0; i < 4; i++) {
        int n2 = bx * 32 + ty + i * 8;
        WT[(size_t)n2 * K + k2] = (__bf16)tile[tx][ty + i * 8];
    }
}

// ---------------------------------------------------------------------------
// transpose bf16: V [R][C] -> VT [C][R]
// ---------------------------------------------------------------------------
__global__ void transpose_bf16_kernel(const __bf16* __restrict__ V, __bf16* __restrict__ VT,
                                      int R, int C) {
    __shared__ __bf16 tile[32][33];
    int bx = blockIdx.x;  // over C/32
    int by = blockIdx.y;  // over R/32
    int tx = threadIdx.x;
    int ty = threadIdx.y;
#pragma unroll
    for (int i = 0; i < 4; i++)
        tile[ty + i * 8][tx] = V[(size_t)(by * 32 + ty + i * 8) * C + bx * 32 + tx];
    __syncthreads();
#pragma unroll
    for (int i = 0; i < 4; i++)
        VT[(size_t)(bx * 32 + ty + i * 8) * R + by * 32 + tx] = tile[tx][ty + i * 8];
}

// ---------------------------------------------------------------------------
// NT GEMM: C[M,N] = A[M,K] * BT[N,K]^T   (bf16 in, fp32 accum, OUT_T out)
// 128x128 tile, BK=32, 256 threads = 4 waves, each wave 64x64 (4x4 MFMA tiles)
// MFMA layouts (HW-verified): A: m=lane&15, k=quad*8+j; B: n=lane&15, k=quad*8+j
//                             C/D: col=lane&15, row=quad*4+reg
// ---------------------------------------------------------------------------
template <typename OUT_T>
__global__ __launch_bounds__(256) void gemm_bt_kernel(const __bf16* __restrict__ A,
                                                      const __bf16* __restrict__ BT,
                                                      OUT_T* __restrict__ C,
                                                      int M, int N, int K) {
    __shared__ __bf16 As[128 * 40];  // +8 pad: lane stride 80B -> 2-way (free)
    __shared__ __bf16 Bs[128 * 40];
    int n0 = blockIdx.x * 128;
    int m0 = blockIdx.y * 128;
    int tid = threadIdx.x;
    int wave = tid >> 6, lane = tid & 63, quad = lane >> 4, l16 = lane & 15;
    int wm = (wave >> 1) * 64, wn = (wave & 1) * 64;

    f32x4 acc[4][4] = {};

    for (int kb = 0; kb < K; kb += 32) {
        __syncthreads();  // protect LDS reuse from previous iteration reads
#pragma unroll
        for (int i = 0; i < 2; i++) {
            int c = tid + i * 256;           // 512 chunks of 8 elems
            int row = c >> 2, col8 = (c & 3) * 8;
            *reinterpret_cast<bf16x8*>(&As[row * 40 + col8]) =
                *reinterpret_cast<const bf16x8*>(&A[(size_t)(m0 + row) * K + kb + col8]);
            *reinterpret_cast<bf16x8*>(&Bs[row * 40 + col8]) =
                *reinterpret_cast<const bf16x8*>(&BT[(size_t)(n0 + row) * K + kb + col8]);
        }
        __syncthreads();
        bf16x8 af[4], bfr[4];
#pragma unroll
        for (int mt = 0; mt < 4; mt++)
            af[mt] = *reinterpret_cast<const bf16x8*>(&As[(wm + mt * 16 + l16) * 40 + quad * 8]);
#pragma unroll
        for (int nt = 0; nt < 4; nt++)
            bfr[nt] = *reinterpret_cast<const bf16x8*>(&Bs[(wn + nt * 16 + l16) * 40 + quad * 8]);
#pragma unroll
        for (int mt = 0; mt < 4; mt++)
#pragma unroll
            for (int nt = 0; nt < 4; nt++)
                acc[mt][nt] = __builtin_amdgcn_mfma_f32_16x16x32_bf16(af[mt], bfr[nt],
                                                                      acc[mt][nt], 0, 0, 0);
    }

#pragma unroll
    for (int mt = 0; mt < 4; mt++)
#pragma unroll
        for (int nt = 0; nt < 4; nt++)
#pragma unroll
            for (int r = 0; r < 4; r++) {
                int row = m0 + wm + mt * 16 + quad * 4 + r;
                int col = n0 + wn + nt * 16 + l16;
                C[(size_t)row * N + col] = (OUT_T)acc[mt][nt][r];
            }
}

// ---------------------------------------------------------------------------
// Flash attention (causal, GQA). One block = (head h, 128-row Q tile).
// 4 waves x 32 q-rows each. KV tiles of 64. Q/K direct from global,
// V from pre-transposed VT [KV_COLS][S]. P round-trips through per-wave LDS.
// ---------------------------------------------------------------------------
__global__ __launch_bounds__(256) void attn_kernel(const __bf16* __restrict__ Q,
                                                   const __bf16* __restrict__ Kb,
                                                   const __bf16* __restrict__ VT,
                                                   __bf16* __restrict__ Ao) {
    __shared__ __bf16 Pl[4][32 * 72];
    int qt = blockIdx.x;     // 16 q-tiles
    int h = blockIdx.y;      // 32 heads
    int kvh = h >> 2;        // GQA: 4 q-heads per kv-head
    int tid = threadIdx.x;
    int wave = tid >> 6, lane = tid & 63, quad = lane >> 4, l16 = lane & 15;
    int q0 = qt * 128;
    int wq = q0 + wave * 32;

    // Q fragments held in registers for the whole KV loop (32 rows x 128 k per wave)
    bf16x8 qf[2][4];
#pragma unroll
    for (int m = 0; m < 2; m++)
#pragma unroll
        for (int ks = 0; ks < 4; ks++)
            qf[m][ks] = *reinterpret_cast<const bf16x8*>(
                &Q[(size_t)(wq + m * 16 + l16) * HID + h * HD + ks * 32 + quad * 8]);

    f32x4 acc_o[2][8] = {};
    float mstate[2][4], lstate[2][4];
#pragma unroll
    for (int m = 0; m < 2; m++)
#pragma unroll
        for (int r = 0; r < 4; r++) { mstate[m][r] = -1e30f; lstate[m][r] = 0.f; }

    const float scale = 0.0883883476483184f;  // 1/sqrt(128)
    int ntiles = qt * 2 + 2;                  // causal: only tiles with kv0 <= q0+127
    __bf16* Pw = Pl[wave];

    for (int t = 0; t < ntiles; t++) {
        int kv0 = t * 64;
        // ---- S = Q K^T (2 m-tiles x 4 n-tiles, K-dim 128 = 4 MFMA steps)
        f32x4 sacc[2][4] = {};
#pragma unroll
        for (int ks = 0; ks < 4; ks++) {
            bf16x8 kf[4];
#pragma unroll
            for (int n = 0; n < 4; n++)
                kf[n] = *reinterpret_cast<const bf16x8*>(
                    &Kb[(size_t)(kv0 + n * 16 + l16) * KV_COLS + kvh * HD + ks * 32 + quad * 8]);
#pragma unroll
            for (int m = 0; m < 2; m++)
#pragma unroll
                for (int n = 0; n < 4; n++)
                    sacc[m][n] = __builtin_amdgcn_mfma_f32_16x16x32_bf16(qf[m][ks], kf[n],
                                                                         sacc[m][n], 0, 0, 0);
        }
        // ---- online softmax (rows live on (quad, r); cols on l16; reduce width 16)
#pragma unroll
        for (int m = 0; m < 2; m++) {
#pragma unroll
            for (int r = 0; r < 4; r++) {
                int row = wq + m * 16 + quad * 4 + r;
                float vals[4];
                float rowmax = -1e30f;
#pragma unroll
                for (int n = 0; n < 4; n++) {
                    int col = kv0 + n * 16 + l16;
                    float v = sacc[m][n][r] * scale;
                    if (col > row) v = -1e30f;  // causal mask
                    vals[n] = v;
                    rowmax = fmaxf(rowmax, v);
                }
#pragma unroll
                for (int off = 8; off >= 1; off >>= 1)
                    rowmax = fmaxf(rowmax, __shfl_xor(rowmax, off, 16));
                float mnew = fmaxf(mstate[m][r], rowmax);
                float alpha = __expf(mstate[m][r] - mnew);
                float rsum = 0.f;
#pragma unroll
                for (int n = 0; n < 4; n++) {
                    float p = __expf(vals[n] - mnew);
                    rsum += p;
                    Pw[(m * 16 + quad * 4 + r) * 72 + n * 16 + l16] = (__bf16)p;
                }
#pragma unroll
                for (int off = 8; off >= 1; off >>= 1)
                    rsum += __shfl_xor(rsum, off, 16);
                lstate[m][r] = lstate[m][r] * alpha + rsum;
                mstate[m][r] = mnew;
#pragma unroll
                for (int dn = 0; dn < 8; dn++)
                    acc_o[m][dn][r] *= alpha;
            }
        }
        __syncthreads();  // make P (C-layout) visible before A-layout re-read
        // ---- O += P V  (K-dim 64 = 2 MFMA steps; B-frags from VT, contiguous)
#pragma unroll
        for (int ks = 0; ks < 2; ks++) {
            bf16x8 pf[2];
#pragma unroll
            for (int m = 0; m < 2; m++)
                pf[m] = *reinterpret_cast<const bf16x8*>(
                    &Pw[(m * 16 + l16) * 72 + ks * 32 + quad * 8]);
#pragma unroll
            for (int dn = 0; dn < 8; dn++) {
                bf16x8 vf = *reinterpret_cast<const bf16x8*>(
                    &VT[(size_t)(kvh * HD + dn * 16 + l16) * S_LEN + kv0 + ks * 32 + quad * 8]);
#pragma unroll
                for (int m = 0; m < 2; m++)
                    acc_o[m][dn] = __builtin_amdgcn_mfma_f32_16x16x32_bf16(pf[m], vf,
                                                                           acc_o[m][dn], 0, 0, 0);
            }
        }
        __syncthreads();  // Pw reuse next iteration
    }

    // ---- epilogue: normalize and store (bf16, [S, H*D], head h -> cols h*128..)
#pragma unroll
    for (int m = 0; m < 2; m++)
#pragma unroll
        for (int dn = 0; dn < 8; dn++)
#pragma unroll
            for (int r = 0; r < 4; r++) {
                int row = wq + m * 16 + quad * 4 + r;
                int col = h * HD + dn * 16 + l16;
                Ao[(size_t)row * HID + col] = (__bf16)(acc_o[m][dn][r] / lstate[m][r]);
            }
}

// ---------------------------------------------------------------------------
extern "C" void kernel_launch(void* const* d_in, const int* in_sizes, int n_in,
                              void* d_out, int out_size, void* d_ws, size_t ws_size,
                              hipStream_t stream) {
    const float* hs = (const float*)d_in[0];
    // d_in[1] = attention_mask (pure causal; applied analytically)
    const float* wq = (const float*)d_in[2];
    const float* wk = (const float*)d_in[3];
    const float* wv = (const float*)d_in[4];
    const float* wo = (const float*)d_in[5];
    float* out = (float*)d_out;

    char* ws = (char*)d_ws;
    // workspace layout (92 MB total, with reuse)
    __bf16* WqT = (__bf16*)(ws + (size_t)0);          // 32 MB [4096][4096] (reused for WoT)
    __bf16* WkT = (__bf16*)(ws + ((size_t)32 << 20)); //  8 MB [1024][4096]
    __bf16* WvT = (__bf16*)(ws + ((size_t)40 << 20)); //  8 MB [1024][4096]
    __bf16* Xb  = (__bf16*)(ws + ((size_t)48 << 20)); // 16 MB [2048][4096] (reused for attn out)
    __bf16* Qb  = (__bf16*)(ws + ((size_t)64 << 20)); // 16 MB [2048][4096]
    __bf16* Kb  = (__bf16*)(ws + ((size_t)80 << 20)); //  4 MB [2048][1024]
    __bf16* Vb  = (__bf16*)(ws + ((size_t)84 << 20)); //  4 MB [2048][1024]
    __bf16* VTg = (__bf16*)(ws + ((size_t)88 << 20)); //  4 MB [1024][2048]
    __bf16* Ab  = Xb;  // attention output reuses Xb (Xb dead after V gemm)

    const int nX = S_LEN * HID;  // 8M

    // 1) cast hidden to bf16
    cast_bf16_kernel<<<nX / 4 / 256, 256, 0, stream>>>(hs, Xb, nX);
    // 2) Q = Xb @ WqT^T
    transpose_cast_kernel<<<dim3(HID / 32, HID / 32), dim3(32, 8), 0, stream>>>(wq, WqT, HID, HID);
    gemm_bt_kernel<__bf16><<<dim3(HID / 128, S_LEN / 128), 256, 0, stream>>>(
        Xb, WqT, Qb, S_LEN, HID, HID);
    // 3) K = Xb @ WkT^T
    transpose_cast_kernel<<<dim3(KV_COLS / 32, HID / 32), dim3(32, 8), 0, stream>>>(wk, WkT, HID, KV_COLS);
    gemm_bt_kernel<__bf16><<<dim3(KV_COLS / 128, S_LEN / 128), 256, 0, stream>>>(
        Xb, WkT, Kb, S_LEN, KV_COLS, HID);
    // 4) V = Xb @ WvT^T, then V^T for PV fragment reads
    transpose_cast_kernel<<<dim3(KV_COLS / 32, HID / 32), dim3(32, 8), 0, stream>>>(wv, WvT, HID, KV_COLS);
    gemm_bt_kernel<__bf16><<<dim3(KV_COLS / 128, S_LEN / 128), 256, 0, stream>>>(
        Xb, WvT, Vb, S_LEN, KV_COLS, HID);
    transpose_bf16_kernel<<<dim3(KV_COLS / 32, S_LEN / 32), dim3(32, 8), 0, stream>>>(
        Vb, VTg, S_LEN, KV_COLS);
    // 5) flash attention -> Ab (overwrites Xb; safe)
    attn_kernel<<<dim3(16, 32), 256, 0, stream>>>(Qb, Kb, VTg, Ab);
    // 6) out = Ab @ WoT^T (fp32 out). WoT reuses WqT space.
    transpose_cast_kernel<<<dim3(HID / 32, HID / 32), dim3(32, 8), 0, stream>>>(wo, WqT, HID, HID);
    gemm_bt_kernel<float><<<dim3(HID / 128, S_LEN / 128), 256, 0, stream>>>(
        Ab, WqT, out, S_LEN, HID, HID);
}